// Round 5
// baseline (421.192 us; speedup 1.0000x reference)
//
#include <hip/hip_runtime.h>
#include <stdint.h>

typedef unsigned short u16;
typedef __attribute__((ext_vector_type(8))) short short8;
typedef __attribute__((ext_vector_type(4))) float f32x4;
typedef __attribute__((ext_vector_type(16))) float f32x16;

#define B_ 2
#define S_ 2048
#define E_ 2048
#define H_ 16
#define D_ 128
#define M_ 4096

__device__ __forceinline__ u16 f2bf(float f) {
  unsigned u = __float_as_uint(f);
  u = u + 0x7FFFu + ((u >> 16) & 1u);
  return (u16)(u >> 16);
}
__device__ __forceinline__ float bf2f(u16 h) {
  return __uint_as_float(((unsigned)h) << 16);
}

// async global->LDS, 16B per lane; LDS dest is wave-uniform base + lane*16
#define GLD16(gp, lp) __builtin_amdgcn_global_load_lds(                      \
    (__attribute__((address_space(1))) void*)(gp),                           \
    (__attribute__((address_space(3))) void*)(lp), 16, 0, 0)

// ---------------------------------------------------------------- cast f32->bf16
__global__ void cast_bf16(const float4* __restrict__ src, ushort4* __restrict__ dst, int n4) {
  int i = blockIdx.x * 256 + threadIdx.x;
  if (i < n4) {
    float4 v = src[i];
    ushort4 o;
    o.x = f2bf(v.x); o.y = f2bf(v.y); o.z = f2bf(v.z); o.w = f2bf(v.w);
    dst[i] = o;
  }
}

// 4 weight casts in one launch (blockIdx.y selects the tensor); o0..o2 contiguous -> [Wq;Wk;Wv]
__global__ void cast4_bf16(const float4* __restrict__ w0, const float4* __restrict__ w1,
                           const float4* __restrict__ w2, const float4* __restrict__ w3,
                           ushort4* __restrict__ o0, ushort4* __restrict__ o1,
                           ushort4* __restrict__ o2, ushort4* __restrict__ o3, int n4) {
  const int i = blockIdx.x * 256 + threadIdx.x;
  if (i >= n4) return;
  const float4* s; ushort4* d;
  switch (blockIdx.y) {
    case 0: s = w0; d = o0; break;
    case 1: s = w1; d = o1; break;
    case 2: s = w2; d = o2; break;
    default: s = w3; d = o3; break;
  }
  float4 v = s[i];
  ushort4 o;
  o.x = f2bf(v.x); o.y = f2bf(v.y); o.z = f2bf(v.z); o.w = f2bf(v.w);
  d[i] = o;
}

// ---------------------------------------------------------------- GEMM  C = A[M,K] @ W[N,K]^T
// m97-style: 128x128 tile, BK=32, 4 waves (each 64x64 = 4x4 frags of 16x16x32)
// MODE 0: fused QKV (N=6144): nn>>11 selects tensor; Q,K -> [B,H,S,D] bf16; V -> [B,H,D,S] bf16
//         (transpose folded into the scattered epilogue store). Cp = Qb base; Kb/VTb at +NX/+2NX.
// MODE 1: write f32 row-major [M,N]
template <int MODE>
__launch_bounds__(256, 2)
__global__ void gemm_bt(const u16* __restrict__ A, const u16* __restrict__ Bw,
                        void* __restrict__ Cp, int M, int N, int K) {
  __shared__ alignas(16) u16 As[128 * 32];
  __shared__ alignas(16) u16 Bs[128 * 32];
  const int tid = threadIdx.x;
  const int wave = tid >> 6, lane = tid & 63;
  const int m0 = blockIdx.y * 128, n0 = blockIdx.x * 128;
  const int wr = (wave >> 1) * 64, wc = (wave & 1) * 64;
  const int lrow = lane & 15, lk = (lane >> 4) * 8;
  f32x4 acc[4][4] = {};

  for (int k0 = 0; k0 < K; k0 += 32) {
#pragma unroll
    for (int q = 0; q < 2; ++q) {
      const int g = q * 4 + wave;        // 0..7 (wave-uniform)
      const int c = g * 64 + lane;       // 16B-chunk id, 0..511
      const int row = c >> 2, ch = (c & 3) * 8;
      GLD16(A + (size_t)(m0 + row) * K + k0 + ch, &As[g * 512]);
      GLD16(Bw + (size_t)(n0 + row) * K + k0 + ch, &Bs[g * 512]);
    }
    __syncthreads();
    short8 a[4], b[4];
#pragma unroll
    for (int m = 0; m < 4; ++m) a[m] = *(const short8*)&As[(wr + m * 16 + lrow) * 32 + lk];
#pragma unroll
    for (int n = 0; n < 4; ++n) b[n] = *(const short8*)&Bs[(wc + n * 16 + lrow) * 32 + lk];
#pragma unroll
    for (int m = 0; m < 4; ++m)
#pragma unroll
      for (int n = 0; n < 4; ++n)
        acc[m][n] = __builtin_amdgcn_mfma_f32_16x16x32_bf16(a[m], b[n], acc[m][n], 0, 0, 0);
    __syncthreads();
  }

  const int rbase = (lane >> 4) * 4;  // C/D: col = lane&15, row = (lane>>4)*4 + r
#pragma unroll
  for (int m = 0; m < 4; ++m)
#pragma unroll
    for (int n = 0; n < 4; ++n)
#pragma unroll
      for (int r = 0; r < 4; ++r) {
        const int mm = m0 + wr + m * 16 + rbase + r;
        const int nn = n0 + wc + n * 16 + lrow;
        const float v = acc[m][n][r];
        if (MODE == 0) {
          const size_t NXc = (size_t)B_ * S_ * E_;
          const int bb = mm >> 11, s = mm & (S_ - 1);
          const int tz = nn >> 11, nc = nn & 2047;      // tz uniform per block (n0 % 128 == 0)
          const int h = nc >> 7, d = nc & (D_ - 1);
          u16* dst = (u16*)Cp;
          if (tz == 0)
            dst[(((size_t)bb * H_ + h) * S_ + s) * D_ + d] = f2bf(v);
          else if (tz == 1)
            dst[NXc + (((size_t)bb * H_ + h) * S_ + s) * D_ + d] = f2bf(v);
          else
            dst[2 * NXc + (((size_t)bb * H_ + h) * D_ + d) * S_ + s] = f2bf(v);
        } else {
          ((float*)Cp)[(size_t)mm * N + nn] = v;
        }
      }
}

// ---------------------------------------------------------------- RoPE (NeoX) in-place on Q and K, [B,H,S,D] bf16
// Vectorized: 8 d-elements per thread. Q additionally pre-scaled by (1/sqrt(D))*log2(e).
__global__ void rope2_k(u16* __restrict__ Qb, u16* __restrict__ Kb,
                        const float* __restrict__ cosT, const float* __restrict__ sinT) {
  const int y = blockIdx.y;
  u16* T = y ? Kb : Qb;
  const float sc = y ? 1.f : 0.12751744154f;  // 0.0883883476 * 1.4426950409
  const int idx = blockIdx.x * 256 + threadIdx.x;  // B*H*S*8 threads per tensor
  const int row = idx >> 3;                        // (b*H+h)*S + s
  const int d0 = (idx & 7) * 8;
  const int s = row & (S_ - 1);
  const size_t base = (size_t)row * D_;
  short8 lo = *(const short8*)&T[base + d0];
  short8 hv = *(const short8*)&T[base + d0 + 64];
  float c1v[8], s1v[8], c2v[8], s2v[8];
  *(float4*)&c1v[0] = *(const float4*)&cosT[s * D_ + d0];
  *(float4*)&c1v[4] = *(const float4*)&cosT[s * D_ + d0 + 4];
  *(float4*)&s1v[0] = *(const float4*)&sinT[s * D_ + d0];
  *(float4*)&s1v[4] = *(const float4*)&sinT[s * D_ + d0 + 4];
  *(float4*)&c2v[0] = *(const float4*)&cosT[s * D_ + d0 + 64];
  *(float4*)&c2v[4] = *(const float4*)&cosT[s * D_ + d0 + 68];
  *(float4*)&s2v[0] = *(const float4*)&sinT[s * D_ + d0 + 64];
  *(float4*)&s2v[4] = *(const float4*)&sinT[s * D_ + d0 + 68];
  short8 olo, ohi;
#pragma unroll
  for (int j = 0; j < 8; ++j) {
    const float x1 = bf2f((u16)lo[j]), x2 = bf2f((u16)hv[j]);
    olo[j] = (short)f2bf((x1 * c1v[j] - x2 * s1v[j]) * sc);
    ohi[j] = (short)f2bf((x2 * c2v[j] + x1 * s2v[j]) * sc);
  }
  *(short8*)&T[base + d0] = olo;
  *(short8*)&T[base + d0 + 64] = ohi;
}

// ---------------------------------------------------------------- causal flash attention v5
// 16 waves (1024 thr), 4 KV-parity groups x 4 q-subwaves. KVBLK=32, double-buffered per group.
// Tiles per seg = 4t+4, divisible by 4 -> every group does exactly t+1 tiles (no idle/masked
// divergence). Pairing (15-p, p) -> uniform 17 iters per block. 4 waves/SIMD occupancy.
// Merge: 2-round LDS tree (grp1,3 -> grp0,2 -> grp0), SB reused as 128 KB O-buffer.
__launch_bounds__(1024, 4)
__global__ void attn_fwd(const u16* __restrict__ Q, const u16* __restrict__ Kt,
                         const u16* __restrict__ VT, u16* __restrict__ Out) {
  __shared__ alignas(16) u16 SB[4][2][8192];   // [grp][buf][ K 32x128 | V^T 128x32 ]
  __shared__ float MLB[3][4][64][2];
  const int tid = threadIdx.x, wave = tid >> 6, lane = tid & 63;
  const int grp = wave >> 2, w4 = wave & 3;
  // bijective XCD swizzle (256 % 8 == 0): 4 heads per XCD
  const int hw = blockIdx.x;
  const int lid = (hw & 7) * 32 + (hw >> 3);
  const int p = lid & 7, bh = lid >> 3;
  const int bb = bh >> 4, h = bh & 15;
  const u16* Qh = Q + (size_t)bh * S_ * D_;
  const u16* Kh = Kt + (size_t)bh * S_ * D_;
  const u16* Vh = VT + (size_t)bh * D_ * S_;
  const int l31 = lane & 31, hi = lane >> 5;

  auto stage = [&](int buf, int kv0) {   // my group's 4 waves stage my stream (K 8KB + V 8KB)
#pragma unroll
    for (int pp = 0; pp < 2; ++pp) {
      const int g = pp * 4 + w4;       // 0..7 (wave-uniform)
      const int c = g * 64 + lane;     // 0..511
      const int srow = c >> 4, dch = c & 15;
      GLD16(Kh + (size_t)(kv0 + srow) * D_ + ((dch ^ (srow & 7)) * 8), &SB[grp][buf][g * 512]);
      const int drow = c >> 2, sch = c & 3;
      GLD16(Vh + (size_t)drow * S_ + kv0 + ((sch ^ (drow & 3)) * 8), &SB[grp][buf][4096 + g * 512]);
    }
  };

  float* obufA = (float*)&SB[0][0][0];   // 64 KB (streams 0,1) - merge region A
  float* obufB = obufA + 16384;          // 64 KB (streams 2,3) - merge region B

  const int qts[2] = {15 - p, p};
#pragma unroll 1
  for (int seg = 0; seg < 2; ++seg) {
    const int t = qts[seg];
    const int iters = t + 1;             // my group's KV32 tiles: tix = i*4 + grp
    const int q0 = t * 128 + w4 * 32;
    const int qg = q0 + l31;

    // Q fragments (B-operand): lane holds Q[qg][m*16 + hi*8 + j], j=0..7
    short8 qf[8];
#pragma unroll
    for (int m = 0; m < 8; ++m)
      qf[m] = *(const short8*)&Qh[(size_t)qg * D_ + m * 16 + hi * 8];

    f32x16 od[4] = {};   // out^T: od[dt], d = dt*32 + (reg&3)+8*(reg>>2)+4*hi, col q = l31
    float mr = 0.f, lsum = 0.f;          // mr init 0: masked tiles give exp2(-1e30) = 0

    stage(0, grp * 32);
    int cur = 0;

    for (int i = 0; i < iters; ++i) {
      __syncthreads();  // all streams' buf[cur] staged; prior reads of buf[cur^1] done
      if (i + 1 < iters) stage(cur ^ 1, ((i + 1) * 4 + grp) * 32);
      const int kv0 = (i * 4 + grp) * 32;
      const u16* Kc = &SB[grp][cur][0];
      const u16* Vc = &SB[grp][cur][4096];

      // QK^T swapped: S^T[k][q] for 32 kv rows
      f32x16 s0 = {};
      __builtin_amdgcn_s_setprio(1);
#pragma unroll
      for (int m = 0; m < 8; ++m) {
        const int col = m * 16 + hi * 8;
        short8 k0 = *(const short8*)&Kc[l31 * 128 + (col ^ ((l31 & 7) << 3))];
        s0 = __builtin_amdgcn_mfma_f32_32x32x16_bf16(k0, qf[m], s0, 0, 0, 0);
      }
      __builtin_amdgcn_s_setprio(0);

      // causal mask
      if (kv0 + 31 > q0) {
#pragma unroll
        for (int r = 0; r < 16; ++r) {
          const int kg = kv0 + (r & 3) + 8 * (r >> 2) + 4 * hi;
          if (kg > qg) s0[r] = -1e30f;
        }
      }

      // online softmax (scores in log2 units via pre-scaled Q)
      float m0 = fmaxf(s0[0], s0[1]), m1 = fmaxf(s0[2], s0[3]);
      float m2 = fmaxf(s0[4], s0[5]), m3 = fmaxf(s0[6], s0[7]);
      float m4 = fmaxf(s0[8], s0[9]), m5 = fmaxf(s0[10], s0[11]);
      float m6 = fmaxf(s0[12], s0[13]), m7 = fmaxf(s0[14], s0[15]);
      float mloc = fmaxf(fmaxf(fmaxf(m0, m1), fmaxf(m2, m3)),
                         fmaxf(fmaxf(m4, m5), fmaxf(m6, m7)));
      const float mx = fmaxf(mloc, __shfl_xor(mloc, 32));
      const bool need = !__all(mx <= mr + 8.f);   // defer-max (T13)
      float corr = 1.f;
      if (need) {
        const float mnew = fmaxf(mr, mx);
        corr = exp2f(mr - mnew);
        mr = mnew;
      }
      float sloc = 0.f;
#pragma unroll
      for (int r = 0; r < 16; ++r) { s0[r] = exp2f(s0[r] - mr); sloc += s0[r]; }
      const float rsum = sloc + __shfl_xor(sloc, 32);
      lsum = lsum * corr + rsum;
      if (need) {
#pragma unroll
        for (int dt = 0; dt < 4; ++dt)
#pragma unroll
          for (int r = 0; r < 16; ++r) od[dt][r] *= corr;
      }

      // pack P to bf16 words: W0[c][pr] covers k32 = 8c + 4hi + {2pr, 2pr+1}
      unsigned W0[4][2];
#pragma unroll
      for (int c = 0; c < 4; ++c)
#pragma unroll
        for (int pr = 0; pr < 2; ++pr)
          asm("v_cvt_pk_bf16_f32 %0, %1, %2"
              : "=v"(W0[c][pr]) : "v"(s0[4 * c + 2 * pr]), "v"(s0[4 * c + 2 * pr + 1]));

      // PV: out^T += V^T * P^T ; B-frag for group kk needs k = kk*16 + hi*8 + j
      __builtin_amdgcn_s_setprio(1);
#pragma unroll
      for (int kk = 0; kk < 2; ++kk) {
        const int cown = 2 * kk + hi, csend = 2 * kk + 1 - hi;
        const unsigned o0 = W0[cown][0], o1 = W0[cown][1];
        const unsigned r0 = (unsigned)__shfl_xor((int)W0[csend][0], 32);
        const unsigned r1 = (unsigned)__shfl_xor((int)W0[csend][1], 32);
        uint4 bw;
        if (hi == 0) bw = make_uint4(o0, o1, r0, r1);
        else         bw = make_uint4(r0, r1, o0, o1);
        const short8 pf = *(const short8*)&bw;
        const int slot = 2 * kk + hi;    // V chunk col for this k-16 group
#pragma unroll
        for (int dt = 0; dt < 4; ++dt) {
          const int row = dt * 32 + l31;
          const short8 vf = *(const short8*)&Vc[row * 32 + ((slot ^ (row & 3)) * 8)];
          od[dt] = __builtin_amdgcn_mfma_f32_32x32x16_bf16(vf, pf, od[dt], 0, 0, 0);
        }
      }
      __builtin_amdgcn_s_setprio(0);
      cur ^= 1;
    }

    // ---- 2-round merge tree: (1->0), (3->2), then (2->0) ----
    __syncthreads();                      // all compute done; SB reusable as O-buffer
    if (grp == 1 || grp == 3) {
      float* ob = (grp == 1) ? obufA : obufB;
      MLB[grp - 1][w4][lane][0] = mr;
      MLB[grp - 1][w4][lane][1] = lsum;
#pragma unroll
      for (int dt = 0; dt < 4; ++dt)
#pragma unroll
        for (int r = 0; r < 16; ++r)
          ob[(dt * 16 + r) * 256 + w4 * 64 + lane] = od[dt][r];   // lane-major: conflict-free
    }
    __syncthreads();
    if (grp == 0 || grp == 2) {
      const float* ob = (grp == 0) ? obufA : obufB;
      const float mB = MLB[grp][w4][lane][0];     // grp0 reads slot0 (grp1), grp2 slot2 (grp3)
      const float lB = MLB[grp][w4][lane][1];
      const float m = fmaxf(mr, mB);
      const float aA = exp2f(mr - m), aB = exp2f(mB - m);
      lsum = lsum * aA + lB * aB;
      mr = m;
#pragma unroll
      for (int dt = 0; dt < 4; ++dt)
#pragma unroll
        for (int r = 0; r < 16; ++r)
          od[dt][r] = od[dt][r] * aA + ob[(dt * 16 + r) * 256 + w4 * 64 + lane] * aB;
    }
    __syncthreads();
    if (grp == 2) {
      MLB[1][w4][lane][0] = mr;
      MLB[1][w4][lane][1] = lsum;
#pragma unroll
      for (int dt = 0; dt < 4; ++dt)
#pragma unroll
        for (int r = 0; r < 16; ++r)
          obufA[(dt * 16 + r) * 256 + w4 * 64 + lane] = od[dt][r];
    }
    __syncthreads();
    if (grp == 0) {
      const float mB = MLB[1][w4][lane][0];
      const float lB = MLB[1][w4][lane][1];
      const float m = fmaxf(mr, mB);
      const float aA = exp2f(mr - m), aB = exp2f(mB - m);
      lsum = lsum * aA + lB * aB;
#pragma unroll
      for (int dt = 0; dt < 4; ++dt)
#pragma unroll
        for (int r = 0; r < 16; ++r)
          od[dt][r] = od[dt][r] * aA + obufA[(dt * 16 + r) * 256 + w4 * 64 + lane] * aB;

      // finalize: o /= l, write bf16 to attn buffer laid out [B,S,E]
      const float inv = 1.f / lsum;
      const size_t obase = ((size_t)bb * S_ + qg) * E_ + h * D_;
#pragma unroll
      for (int dt = 0; dt < 4; ++dt)
#pragma unroll
        for (int g = 0; g < 4; ++g) {
          ushort4 w;
          w.x = f2bf(od[dt][4 * g + 0] * inv);
          w.y = f2bf(od[dt][4 * g + 1] * inv);
          w.z = f2bf(od[dt][4 * g + 2] * inv);
          w.w = f2bf(od[dt][4 * g + 3] * inv);
          *(ushort4*)&Out[obase + dt * 32 + 8 * g + 4 * hi] = w;
        }
    }
    __syncthreads();                      // merge reads done before next seg restages SB
  }
}

// ---------------------------------------------------------------- launcher
extern "C" void kernel_launch(void* const* d_in, const int* in_sizes, int n_in,
                              void* d_out, int out_size, void* d_ws, size_t ws_size,
                              hipStream_t stream) {
  const float* x    = (const float*)d_in[0];
  const float* cosT = (const float*)d_in[1];
  const float* sinT = (const float*)d_in[2];
  const float* Wq   = (const float*)d_in[3];
  const float* Wk   = (const float*)d_in[4];
  const float* Wv   = (const float*)d_in[5];
  const float* Wo   = (const float*)d_in[6];
  float* out = (float*)d_out;

  const size_t NX = (size_t)B_ * S_ * E_;  // 8388608
  const size_t NW = (size_t)E_ * E_;       // 4194304
  u16* ws  = (u16*)d_ws;
  u16* xb  = ws;
  u16* Wqb = xb + NX;        // [Wq;Wk;Wv] contiguous -> fused [6144][2048]
  u16* Wkb = Wqb + NW;
  u16* Wvb = Wkb + NW;
  u16* Wob = Wvb + NW;
  u16* Qb  = Wob + NW;       // Qb, Kb, VTb contiguous (gemm MODE 0 relies on +NX offsets)
  u16* Kb  = Qb + NX;
  u16* VTb = Kb + NX;
  u16* Ab  = VTb + NX;

  cast_bf16<<<(int)(NX / 4 / 256), 256, 0, stream>>>((const float4*)x, (ushort4*)xb, (int)(NX / 4));
  cast4_bf16<<<dim3((int)(NW / 4 / 256), 4), 256, 0, stream>>>(
      (const float4*)Wq, (const float4*)Wk, (const float4*)Wv, (const float4*)Wo,
      (ushort4*)Wqb, (ushort4*)Wkb, (ushort4*)Wvb, (ushort4*)Wob, (int)(NW / 4));

  // fused QKV projection: [4096,2048] x [6144,2048]^T, V written pre-transposed
  gemm_bt<0><<<dim3(48, 32), 256, 0, stream>>>(xb, Wqb, Qb, M_, 3 * E_, E_);

  rope2_k<<<dim3((B_ * H_ * S_ * 8) / 256, 2), 256, 0, stream>>>(Qb, Kb, cosT, sinT);

  attn_fwd<<<dim3(256), 1024, 0, stream>>>(Qb, Kb, VTb, Ab);

  gemm_bt<1><<<dim3(16, 32), 256, 0, stream>>>(Ab, Wob, out, M_, E_, E_);
}

// Round 6
// 289.656 us; speedup vs baseline: 1.4541x; 1.4541x over previous
//
#include <hip/hip_runtime.h>
#include <stdint.h>

typedef unsigned short u16;
typedef __attribute__((ext_vector_type(8))) short short8;
typedef __attribute__((ext_vector_type(4))) float f32x4;
typedef __attribute__((ext_vector_type(16))) float f32x16;

#define B_ 2
#define S_ 2048
#define E_ 2048
#define H_ 16
#define D_ 128
#define M_ 4096

__device__ __forceinline__ u16 f2bf(float f) {
  unsigned u = __float_as_uint(f);
  u = u + 0x7FFFu + ((u >> 16) & 1u);
  return (u16)(u >> 16);
}
__device__ __forceinline__ float bf2f(u16 h) {
  return __uint_as_float(((unsigned)h) << 16);
}

// async global->LDS, 16B per lane; LDS dest is wave-uniform base + lane*16
#define GLD16(gp, lp) __builtin_amdgcn_global_load_lds(                      \
    (__attribute__((address_space(1))) void*)(gp),                           \
    (__attribute__((address_space(3))) void*)(lp), 16, 0, 0)

// ---------------------------------------------------------------- cast f32->bf16
__global__ void cast_bf16(const float4* __restrict__ src, ushort4* __restrict__ dst, int n4) {
  int i = blockIdx.x * 256 + threadIdx.x;
  if (i < n4) {
    float4 v = src[i];
    ushort4 o;
    o.x = f2bf(v.x); o.y = f2bf(v.y); o.z = f2bf(v.z); o.w = f2bf(v.w);
    dst[i] = o;
  }
}

// 4 weight casts in one launch (blockIdx.y selects the tensor); o0..o2 contiguous -> [Wq;Wk;Wv]
__global__ void cast4_bf16(const float4* __restrict__ w0, const float4* __restrict__ w1,
                           const float4* __restrict__ w2, const float4* __restrict__ w3,
                           ushort4* __restrict__ o0, ushort4* __restrict__ o1,
                           ushort4* __restrict__ o2, ushort4* __restrict__ o3, int n4) {
  const int i = blockIdx.x * 256 + threadIdx.x;
  if (i >= n4) return;
  const float4* s; ushort4* d;
  switch (blockIdx.y) {
    case 0: s = w0; d = o0; break;
    case 1: s = w1; d = o1; break;
    case 2: s = w2; d = o2; break;
    default: s = w3; d = o3; break;
  }
  float4 v = s[i];
  ushort4 o;
  o.x = f2bf(v.x); o.y = f2bf(v.y); o.z = f2bf(v.z); o.w = f2bf(v.w);
  d[i] = o;
}

// ---------------------------------------------------------------- GEMM  C = A[M,K] @ W[N,K]^T
// m97-style: 128x128 tile, BK=32, 4 waves (each 64x64 = 4x4 frags of 16x16x32)
// MODE 0: fused QKV (N=6144): tz = nn>>11 selects tensor; ALL write coalesced [B,H,S,D] bf16
//         at Cp + tz*NX (Qb, Kb, Vb contiguous).
// MODE 1: write f32 row-major [M,N]
template <int MODE>
__launch_bounds__(256, 2)
__global__ void gemm_bt(const u16* __restrict__ A, const u16* __restrict__ Bw,
                        void* __restrict__ Cp, int M, int N, int K) {
  __shared__ alignas(16) u16 As[128 * 32];
  __shared__ alignas(16) u16 Bs[128 * 32];
  const int tid = threadIdx.x;
  const int wave = tid >> 6, lane = tid & 63;
  const int m0 = blockIdx.y * 128, n0 = blockIdx.x * 128;
  const int wr = (wave >> 1) * 64, wc = (wave & 1) * 64;
  const int lrow = lane & 15, lk = (lane >> 4) * 8;
  f32x4 acc[4][4] = {};

  for (int k0 = 0; k0 < K; k0 += 32) {
#pragma unroll
    for (int q = 0; q < 2; ++q) {
      const int g = q * 4 + wave;        // 0..7 (wave-uniform)
      const int c = g * 64 + lane;       // 16B-chunk id, 0..511
      const int row = c >> 2, ch = (c & 3) * 8;
      GLD16(A + (size_t)(m0 + row) * K + k0 + ch, &As[g * 512]);
      GLD16(Bw + (size_t)(n0 + row) * K + k0 + ch, &Bs[g * 512]);
    }
    __syncthreads();
    short8 a[4], b[4];
#pragma unroll
    for (int m = 0; m < 4; ++m) a[m] = *(const short8*)&As[(wr + m * 16 + lrow) * 32 + lk];
#pragma unroll
    for (int n = 0; n < 4; ++n) b[n] = *(const short8*)&Bs[(wc + n * 16 + lrow) * 32 + lk];
#pragma unroll
    for (int m = 0; m < 4; ++m)
#pragma unroll
      for (int n = 0; n < 4; ++n)
        acc[m][n] = __builtin_amdgcn_mfma_f32_16x16x32_bf16(a[m], b[n], acc[m][n], 0, 0, 0);
    __syncthreads();
  }

  const int rbase = (lane >> 4) * 4;  // C/D: col = lane&15, row = (lane>>4)*4 + r
#pragma unroll
  for (int m = 0; m < 4; ++m)
#pragma unroll
    for (int n = 0; n < 4; ++n)
#pragma unroll
      for (int r = 0; r < 4; ++r) {
        const int mm = m0 + wr + m * 16 + rbase + r;
        const int nn = n0 + wc + n * 16 + lrow;
        const float v = acc[m][n][r];
        if (MODE == 0) {
          const size_t NXc = (size_t)B_ * S_ * E_;
          const int bb = mm >> 11, s = mm & (S_ - 1);
          const int tz = nn >> 11, nc = nn & 2047;      // tz uniform per block (n0 % 128 == 0)
          const int h = nc >> 7, d = nc & (D_ - 1);
          ((u16*)Cp)[(size_t)tz * NXc + (((size_t)bb * H_ + h) * S_ + s) * D_ + d] = f2bf(v);
        } else {
          ((float*)Cp)[(size_t)mm * N + nn] = v;
        }
      }
}

// ---------------------------------------------------------------- RoPE (NeoX) in-place on Q and K, [B,H,S,D] bf16
// Vectorized: 8 d-elements per thread. Q additionally pre-scaled by (1/sqrt(D))*log2(e).
__global__ void rope2_k(u16* __restrict__ Qb, u16* __restrict__ Kb,
                        const float* __restrict__ cosT, const float* __restrict__ sinT) {
  const int y = blockIdx.y;
  u16* T = y ? Kb : Qb;
  const float sc = y ? 1.f : 0.12751744154f;  // 0.0883883476 * 1.4426950409
  const int idx = blockIdx.x * 256 + threadIdx.x;  // B*H*S*8 threads per tensor
  const int row = idx >> 3;                        // (b*H+h)*S + s
  const int d0 = (idx & 7) * 8;
  const int s = row & (S_ - 1);
  const size_t base = (size_t)row * D_;
  short8 lo = *(const short8*)&T[base + d0];
  short8 hv = *(const short8*)&T[base + d0 + 64];
  float c1v[8], s1v[8], c2v[8], s2v[8];
  *(float4*)&c1v[0] = *(const float4*)&cosT[s * D_ + d0];
  *(float4*)&c1v[4] = *(const float4*)&cosT[s * D_ + d0 + 4];
  *(float4*)&s1v[0] = *(const float4*)&sinT[s * D_ + d0];
  *(float4*)&s1v[4] = *(const float4*)&sinT[s * D_ + d0 + 4];
  *(float4*)&c2v[0] = *(const float4*)&cosT[s * D_ + d0 + 64];
  *(float4*)&c2v[4] = *(const float4*)&cosT[s * D_ + d0 + 68];
  *(float4*)&s2v[0] = *(const float4*)&sinT[s * D_ + d0 + 64];
  *(float4*)&s2v[4] = *(const float4*)&sinT[s * D_ + d0 + 68];
  short8 olo, ohi;
#pragma unroll
  for (int j = 0; j < 8; ++j) {
    const float x1 = bf2f((u16)lo[j]), x2 = bf2f((u16)hv[j]);
    olo[j] = (short)f2bf((x1 * c1v[j] - x2 * s1v[j]) * sc);
    ohi[j] = (short)f2bf((x2 * c2v[j] + x1 * s2v[j]) * sc);
  }
  *(short8*)&T[base + d0] = olo;
  *(short8*)&T[base + d0 + 64] = ohi;
}

// ---------------------------------------------------------------- V [B,H,S,D] -> VT [B,H,D,S]
__global__ void transpose64(const u16* __restrict__ V, u16* __restrict__ VT) {
  __shared__ alignas(16) u16 t[64][72];
  const int bh = blockIdx.z, st = blockIdx.y * 64, dt = blockIdx.x * 64;
  const u16* Vp = V + (size_t)bh * S_ * D_;
  u16* Tp = VT + (size_t)bh * D_ * S_;
  const int tid = threadIdx.x;
#pragma unroll
  for (int p = 0; p < 2; ++p) {
    const int idx = p * 256 + tid;
    const int r = idx >> 3, c8 = (idx & 7) * 8;
    *(short8*)&t[r][c8] = *(const short8*)&Vp[(size_t)(st + r) * D_ + dt + c8];
  }
  __syncthreads();
#pragma unroll
  for (int p = 0; p < 2; ++p) {
    const int idx = p * 256 + tid;
    const int dr = idx >> 3, s8 = (idx & 7) * 8;
    short8 v;
#pragma unroll
    for (int j = 0; j < 8; ++j) v[j] = t[s8 + j][dr];
    *(short8*)&Tp[(size_t)(dt + dr) * S_ + st + s8] = v;
  }
}

// ---------------------------------------------------------------- causal flash attention v4 (proven: 82 us)
// 8 waves x 32q, KV-parity split: waves 0-3 (grp A) even KV64 tiles, waves 4-7 (grp B) odd
// tiles, SAME 128 q-rows, concurrently (2 waves/SIMD). Each group has its own double-buffered
// K/V LDS stream. nt = 2t+2 (even) -> both groups do exactly t+1 steps: barriers uniform.
// Partial (m,l,O) merged through LDS at segment end. mr init = 0 (not -1e30) so a fully
// causal-masked first tile in group B yields p = exp2(-1e30-0) = 0, not exp2(0) = 1.
__launch_bounds__(512, 2)
__global__ void attn_fwd(const u16* __restrict__ Q, const u16* __restrict__ Kt,
                         const u16* __restrict__ VT, u16* __restrict__ Out) {
  // SB[stream][buf]: K tile [64][128] (8192 u16) then V^T tile [128][64] (8192 u16)
  __shared__ alignas(16) u16 SB[2][2][16384];
  __shared__ float MLB[4][64][2];
  const int tid = threadIdx.x, wave = tid >> 6, lane = tid & 63;
  const int grp = wave >> 2, w4 = wave & 3;
  // bijective XCD swizzle (256 % 8 == 0): 4 heads per XCD
  const int hw = blockIdx.x;
  const int lid = (hw & 7) * 32 + (hw >> 3);
  const int p = lid & 7, bh = lid >> 3;
  const int bb = bh >> 4, h = bh & 15;
  const u16* Qh = Q + (size_t)bh * S_ * D_;
  const u16* Kh = Kt + (size_t)bh * S_ * D_;
  const u16* Vh = VT + (size_t)bh * D_ * S_;
  const int l31 = lane & 31, hi = lane >> 5;

  auto stage = [&](int buf, int kv0) {   // 4 waves of my group stage my stream
#pragma unroll
    for (int pp = 0; pp < 4; ++pp) {
      const int g = pp * 4 + w4;       // 0..15 (wave-uniform)
      const int c = g * 64 + lane;     // 0..1023
      const int srow = c >> 4, dch = c & 15;
      GLD16(Kh + (size_t)(kv0 + srow) * D_ + ((dch ^ (srow & 7)) * 8), &SB[grp][buf][g * 512]);
      const int drow = c >> 3, sch = c & 7;
      GLD16(Vh + (size_t)drow * S_ + kv0 + ((sch ^ (drow & 7)) * 8), &SB[grp][buf][8192 + g * 512]);
    }
  };

  float* obuf = (float*)&SB[1][0][0];  // 64 KB merge region (stream 1, both buffers)

  const int qts[2] = {15 - p, p};
#pragma unroll 1
  for (int seg = 0; seg < 2; ++seg) {
    const int t = qts[seg];
    const int iters = t + 1;           // nt = 2t+2 KV64 tiles, split by parity
    const int q0 = t * 128 + w4 * 32;
    const int qg = q0 + l31;

    // Q fragments (B-operand): lane holds Q[qg][m*16 + hi*8 + j], j=0..7
    short8 qf[8];
#pragma unroll
    for (int m = 0; m < 8; ++m)
      qf[m] = *(const short8*)&Qh[(size_t)qg * D_ + m * 16 + hi * 8];

    f32x16 od[4] = {};   // out^T: od[dt], d = dt*32 + (reg&3)+8*(reg>>2)+4*hi, col q = l31
    float mr = 0.f, lsum = 0.f;        // mr init 0: see header comment

    stage(0, grp * 64);                // my first tile = tile grp
    int cur = 0;

    for (int i = 0; i < iters; ++i) {
      __syncthreads();  // both streams' buf[cur] staged; prior reads of buf[cur^1] done
      if (i + 1 < iters) stage(cur ^ 1, (2 * (i + 1) + grp) * 64);
      const int kv0 = (2 * i + grp) * 64;
      const u16* Kc = &SB[grp][cur][0];
      const u16* Vc = &SB[grp][cur][8192];

      // QK^T swapped: S^T[k][q], two 32-kv halves
      f32x16 s0 = {}, s1 = {};
      __builtin_amdgcn_s_setprio(1);
#pragma unroll
      for (int m = 0; m < 8; ++m) {
        const int col = m * 16 + hi * 8;
        const int sw = (l31 & 7) << 3;
        short8 k0 = *(const short8*)&Kc[l31 * 128 + (col ^ sw)];
        short8 k1 = *(const short8*)&Kc[(32 + l31) * 128 + (col ^ sw)];
        s0 = __builtin_amdgcn_mfma_f32_32x32x16_bf16(k0, qf[m], s0, 0, 0, 0);
        s1 = __builtin_amdgcn_mfma_f32_32x32x16_bf16(k1, qf[m], s1, 0, 0, 0);
      }
      __builtin_amdgcn_s_setprio(0);

      // causal mask (only tiles overlapping this wave's diagonal)
      if (kv0 + 63 > q0) {
#pragma unroll
        for (int r = 0; r < 16; ++r) {
          const int k0g = kv0 + (r & 3) + 8 * (r >> 2) + 4 * hi;
          if (k0g > qg)      s0[r] = -1e30f;
          if (k0g + 32 > qg) s1[r] = -1e30f;
        }
      }

      // online softmax (scores already in log2 units via pre-scaled Q)
      float mloc = s0[0];
#pragma unroll
      for (int r = 1; r < 16; ++r) mloc = fmaxf(mloc, s0[r]);
#pragma unroll
      for (int r = 0; r < 16; ++r) mloc = fmaxf(mloc, s1[r]);
      const float mx = fmaxf(mloc, __shfl_xor(mloc, 32));
      const bool need = !__all(mx <= mr + 8.f);   // defer-max (T13)
      float corr = 1.f;
      if (need) {
        const float mnew = fmaxf(mr, mx);
        corr = exp2f(mr - mnew);
        mr = mnew;
      }
      float sloc = 0.f;
#pragma unroll
      for (int r = 0; r < 16; ++r) { s0[r] = exp2f(s0[r] - mr); sloc += s0[r]; }
#pragma unroll
      for (int r = 0; r < 16; ++r) { s1[r] = exp2f(s1[r] - mr); sloc += s1[r]; }
      const float rsum = sloc + __shfl_xor(sloc, 32);
      lsum = lsum * corr + rsum;
      if (need) {
#pragma unroll
        for (int dt = 0; dt < 4; ++dt)
#pragma unroll
          for (int r = 0; r < 16; ++r) od[dt][r] *= corr;
      }

      // pack P to bf16 words: W[half][c][pr] covers k32 = 8c + 4hi + {2pr, 2pr+1}
      unsigned W0[4][2], W1[4][2];
#pragma unroll
      for (int c = 0; c < 4; ++c)
#pragma unroll
        for (int pr = 0; pr < 2; ++pr) {
          asm("v_cvt_pk_bf16_f32 %0, %1, %2"
              : "=v"(W0[c][pr]) : "v"(s0[4 * c + 2 * pr]), "v"(s0[4 * c + 2 * pr + 1]));
          asm("v_cvt_pk_bf16_f32 %0, %1, %2"
              : "=v"(W1[c][pr]) : "v"(s1[4 * c + 2 * pr]), "v"(s1[4 * c + 2 * pr + 1]));
        }

      // PV: out^T += V^T * P^T ; B-frag for group kk needs k = kk*16 + hi*8 + j
      __builtin_amdgcn_s_setprio(1);
#pragma unroll
      for (int kk = 0; kk < 4; ++kk) {
        const int cown = 2 * (kk & 1) + hi, csend = 2 * (kk & 1) + 1 - hi;
        unsigned o0, o1, sd0, sd1;
        if (kk < 2) { o0 = W0[cown][0]; o1 = W0[cown][1]; sd0 = W0[csend][0]; sd1 = W0[csend][1]; }
        else        { o0 = W1[cown][0]; o1 = W1[cown][1]; sd0 = W1[csend][0]; sd1 = W1[csend][1]; }
        const unsigned r0 = (unsigned)__shfl_xor((int)sd0, 32);
        const unsigned r1 = (unsigned)__shfl_xor((int)sd1, 32);
        uint4 bw;
        if (hi == 0) bw = make_uint4(o0, o1, r0, r1);
        else         bw = make_uint4(r0, r1, o0, o1);
        const short8 pf = *(const short8*)&bw;
        const int slot = 2 * kk + hi;
#pragma unroll
        for (int dt = 0; dt < 4; ++dt) {
          const int row = dt * 32 + l31;
          const short8 vf = *(const short8*)&Vc[row * 64 + ((slot ^ (row & 7)) * 8)];
          od[dt] = __builtin_amdgcn_mfma_f32_32x32x16_bf16(vf, pf, od[dt], 0, 0, 0);
        }
      }
      __builtin_amdgcn_s_setprio(0);
      cur ^= 1;
    }

    // ---- merge the two parity partials (group B -> LDS -> group A combines) ----
    __syncthreads();                     // all computes done; stream-1 LDS reusable
    if (grp == 1) {
      MLB[w4][lane][0] = mr;
      MLB[w4][lane][1] = lsum;
#pragma unroll
      for (int dt = 0; dt < 4; ++dt)
#pragma unroll
        for (int r = 0; r < 16; ++r)
          obuf[(dt * 16 + r) * 256 + w4 * 64 + lane] = od[dt][r];  // lane-major: conflict-free
    }
    __syncthreads();
    if (grp == 0) {
      const float mB = MLB[w4][lane][0];
      const float lB = MLB[w4][lane][1];
      const float m = fmaxf(mr, mB);
      const float aA = exp2f(mr - m), aB = exp2f(mB - m);
      lsum = lsum * aA + lB * aB;
#pragma unroll
      for (int dt = 0; dt < 4; ++dt)
#pragma unroll
        for (int r = 0; r < 16; ++r)
          od[dt][r] = od[dt][r] * aA + obuf[(dt * 16 + r) * 256 + w4 * 64 + lane] * aB;

      // finalize: o /= l, write bf16 to attn buffer laid out [B,S,E]
      const float inv = 1.f / lsum;
      const size_t obase = ((size_t)bb * S_ + qg) * E_ + h * D_;
#pragma unroll
      for (int dt = 0; dt < 4; ++dt)
#pragma unroll
        for (int g = 0; g < 4; ++g) {
          ushort4 w;
          w.x = f2bf(od[dt][4 * g + 0] * inv);
          w.y = f2bf(od[dt][4 * g + 1] * inv);
          w.z = f2bf(od[dt][4 * g + 2] * inv);
          w.w = f2bf(od[dt][4 * g + 3] * inv);
          *(ushort4*)&Out[obase + dt * 32 + 8 * g + 4 * hi] = w;
        }
    }
    __syncthreads();                     // merge reads done before next seg restages SB
  }
}

// ---------------------------------------------------------------- launcher
extern "C" void kernel_launch(void* const* d_in, const int* in_sizes, int n_in,
                              void* d_out, int out_size, void* d_ws, size_t ws_size,
                              hipStream_t stream) {
  const float* x    = (const float*)d_in[0];
  const float* cosT = (const float*)d_in[1];
  const float* sinT = (const float*)d_in[2];
  const float* Wq   = (const float*)d_in[3];
  const float* Wk   = (const float*)d_in[4];
  const float* Wv   = (const float*)d_in[5];
  const float* Wo   = (const float*)d_in[6];
  float* out = (float*)d_out;

  const size_t NX = (size_t)B_ * S_ * E_;  // 8388608
  const size_t NW = (size_t)E_ * E_;       // 4194304
  u16* ws  = (u16*)d_ws;
  u16* xb  = ws;
  u16* Wqb = xb + NX;        // [Wq;Wk;Wv] contiguous -> fused [6144][2048]
  u16* Wkb = Wqb + NW;
  u16* Wvb = Wkb + NW;
  u16* Wob = Wvb + NW;
  u16* Qb  = Wob + NW;       // Qb, Kb, Vb contiguous (gemm MODE 0 writes tz*NX offsets)
  u16* Kb  = Qb + NX;
  u16* Vb  = Kb + NX;
  u16* VTb = Vb + NX;
  u16* Ab  = VTb + NX;

  cast_bf16<<<(int)(NX / 4 / 256), 256, 0, stream>>>((const float4*)x, (ushort4*)xb, (int)(NX / 4));
  cast4_bf16<<<dim3((int)(NW / 4 / 256), 4), 256, 0, stream>>>(
      (const float4*)Wq, (const float4*)Wk, (const float4*)Wv, (const float4*)Wo,
      (ushort4*)Wqb, (ushort4*)Wkb, (ushort4*)Wvb, (ushort4*)Wob, (int)(NW / 4));

  // fused QKV projection: [4096,2048] x [6144,2048]^T -> Q,K,V all [B,H,S,D]
  gemm_bt<0><<<dim3(48, 32), 256, 0, stream>>>(xb, Wqb, Qb, M_, 3 * E_, E_);

  rope2_k<<<dim3((B_ * H_ * S_ * 8) / 256, 2), 256, 0, stream>>>(Qb, Kb, cosT, sinT);

  transpose64<<<dim3(D_ / 64, S_ / 64, B_ * H_), 256, 0, stream>>>(Vb, VTb);

  attn_fwd<<<dim3(256), 512, 0, stream>>>(Qb, Kb, VTb, Ab);

  gemm_bt<1><<<dim3(16, 32), 256, 0, stream>>>(Ab, Wob, out, M_, E_, E_);
}